// Round 3
// baseline (588.300 us; speedup 1.0000x reference)
//
#include <hip/hip_runtime.h>
#include <hip/hip_bf16.h>
#include <stdint.h>

// Fused causal MHA, B=256,T=128,H=8,D=256,C=256. One block per (h,b).
// Round 3: X held in registers as MFMA A-fragments (loaded per-lane from
// pre-swizzled bf16 ws) -> projections read only B (W chunks) from LDS.
// LDS cut to 74KB -> 2 blocks/CU (__launch_bounds__(512,4), VGPR<=128).
// 2-slot W ring, 1-ahead issue, counted vmcnt + raw s_barrier.

#define TT 128
#define CC 256
#define DD 256

typedef __attribute__((ext_vector_type(8))) short short8;
typedef __attribute__((ext_vector_type(4))) float f32x4;

// LDS map (75776 B total):
//   [0,32K)       W ring: 2 x 16KB (32 rows x 512B, swizzled by row&7)
//   [32K,64K)     QK chunk ring 2x16KB (Q[128][64B]+K[128][64B]) -> P[128][256B] -> O-half[128][256B]
//   [64K,72K)     VT chunk [32 d][256B]
//   [72K,74K)     softmax reduce scratch
#define LDS_W    0
#define LDS_QK   32768
#define LDS_VT   65536
#define LDS_RED  73728
#define LDS_SIZE 75776

// ws map (needs >= 20054016 B)
#define WS_X    0u
#define WS_WQ   16777216u
#define WS_WK   (16777216u + 1048576u)
#define WS_WV   (16777216u + 2097152u)
#define WS_WP   (16777216u + 3145728u)

#define VMCNT0() asm volatile("s_waitcnt vmcnt(0)" ::: "memory")
#define VMCNT8() asm volatile("s_waitcnt vmcnt(8)" ::: "memory")
#define LGKM0()  asm volatile("s_waitcnt lgkmcnt(0)" ::: "memory")
#define BAR()    do { asm volatile("" ::: "memory"); __builtin_amdgcn_s_barrier(); asm volatile("" ::: "memory"); } while (0)

__device__ __forceinline__ unsigned short f2bf(float x) {
    union { float f; unsigned u; } v; v.f = x;
    unsigned r = v.u + 0x7FFFu + ((v.u >> 16) & 1u);
    return (unsigned short)(r >> 16);
}
__device__ __forceinline__ unsigned pk2(float a, float b) {
    return (unsigned)f2bf(a) | ((unsigned)f2bf(b) << 16);
}
__device__ __forceinline__ int swzr(int row, int byteInRow) {   // 512B/256B rows
    return byteInRow ^ ((row & 7) << 4);
}
__device__ __forceinline__ int swzq(int row, int byteInRow) {   // 64B rows
    return byteInRow ^ (((row >> 2) & 3) << 4);
}

typedef __attribute__((address_space(3))) uint32_t lds_u32;
typedef __attribute__((address_space(1))) const uint32_t glb_u32;

// ---------------- pre-convert: fp32 -> bf16, pre-swizzled 512B rows ----------------
__global__ void convert_pre(const float* __restrict__ x,
                            const float* __restrict__ Wq, const float* __restrict__ Wk,
                            const float* __restrict__ Wv, const float* __restrict__ Wp,
                            char* __restrict__ ws) {
    const int NX = 2097152, NW = 131072, NP = 16384;   // float4 counts
    const int total = NX + 3 * NW + NP;
    for (int i = blockIdx.x * blockDim.x + threadIdx.x; i < total;
         i += gridDim.x * blockDim.x) {
        const float4* src; size_t ob; int li;
        if (i < NX)              { src = (const float4*)x;  ob = WS_X;  li = i; }
        else if (i < NX + NW)    { src = (const float4*)Wq; ob = WS_WQ; li = i - NX; }
        else if (i < NX + 2*NW)  { src = (const float4*)Wk; ob = WS_WK; li = i - NX - NW; }
        else if (i < NX + 3*NW)  { src = (const float4*)Wv; ob = WS_WV; li = i - NX - 2*NW; }
        else                     { src = (const float4*)Wp; ob = WS_WP; li = i - NX - 3*NW; }
        float4 v = src[li];
        uint2 u; u.x = pk2(v.x, v.y); u.y = pk2(v.z, v.w);
        int row = li >> 6, c4 = li & 63;
        *(uint2*)(ws + ob + (size_t)row * 512 + ((c4 * 8) ^ ((row & 7) << 4))) = u;
    }
}

// ---------------- main fused kernel ----------------
__global__ __launch_bounds__(512, 4) void mha_fused(
    const char* __restrict__ ws,
    const float* __restrict__ bq, const float* __restrict__ bk,
    const float* __restrict__ bv, const float* __restrict__ bp,
    float* __restrict__ out)
{
    extern __shared__ __align__(16) char lds[];
    const int tid = threadIdx.x;
    const int w  = tid >> 6, l = tid & 63;
    const int lg = l >> 4, lr = l & 15;
    const int mq = w & 3, nh = w >> 2;        // 4 M-waves x 2 N-waves
    const int bid = blockIdx.x;
    const int h = bid >> 8, b = bid & 255;
    const int am0 = mq * 32 + lr, am1 = am0 + 16;

    auto gl16 = [&](const char* g, int loff) {
        __builtin_amdgcn_global_load_lds((glb_u32*)g, (lds_u32*)(lds + loff), 16, 0, 0);
    };
    // chunk stream: 0..15 = Wq[c]/Wk[c] interleaved, 16..23 = Wv, 24..31 = Wp
    auto chunk_src = [&](int idx) -> const char* {
        if (idx < 16) {
            int c = idx >> 1;
            return ws + ((idx & 1) ? WS_WK : WS_WQ) + (size_t)h * 131072 + (size_t)c * 16384;
        } else if (idx < 24) {
            return ws + WS_WV + (size_t)h * 131072 + (size_t)(idx - 16) * 16384;
        }
        return ws + WS_WP + (size_t)(idx - 24) * 16384;
    };
    auto issue_chunk = [&](int idx) {
        const char* g = chunk_src(idx) + tid * 16;
        int loff = LDS_W + (idx & 1) * 16384 + tid * 16;
        gl16(g, loff);
        gl16(g + 8192, loff + 8192);
    };

    // ---- X as A-fragments in registers (64 VGPR), direct per-lane loads ----
    short8 xf[2][8];
    {
        const char* xp = ws + WS_X + (size_t)b * 65536;
        #pragma unroll
        for (int mt = 0; mt < 2; ++mt) {
            int t = mq * 32 + mt * 16 + lr;
            #pragma unroll
            for (int ks = 0; ks < 8; ++ks)
                xf[mt][ks] = *(const short8*)(xp + t * 512 + swzr(t, ks * 64 + lg * 16));
        }
    }
    issue_chunk(0);
    VMCNT0(); BAR();

    // proj: acc[mt] += X[32t x 256] * Wchunk[32 rows]^T (wave tile 32t x 16n)
    auto proj_mm = [&](int slot, f32x4* acc) {
        const char* Wb = lds + LDS_W + slot * 16384;
        const int br = nh * 16 + lr;
        #pragma unroll
        for (int ks = 0; ks < 8; ++ks) {
            short8 b0 = *(const short8*)(Wb + br * 512 + swzr(br, ks * 64 + lg * 16));
            acc[0] = __builtin_amdgcn_mfma_f32_16x16x32_bf16(xf[0][ks], b0, acc[0], 0, 0, 0);
            acc[1] = __builtin_amdgcn_mfma_f32_16x16x32_bf16(xf[1][ks], b0, acc[1], 0, 0, 0);
        }
    };

    f32x4 sacc[2][4];
    #pragma unroll
    for (int i = 0; i < 2; ++i)
        #pragma unroll
        for (int j = 0; j < 4; ++j) sacc[i][j] = f32x4{0.f,0.f,0.f,0.f};

    // ---- QK phases ----
    #pragma unroll
    for (int c = 0; c < 8; ++c) {
        // Q_c : phase p=2c, consumes chunk 2c (slot 0), issues 2c+1
        issue_chunk(2 * c + 1);
        {
            f32x4 acc[2] = {f32x4{0.f,0.f,0.f,0.f}, f32x4{0.f,0.f,0.f,0.f}};
            proj_mm(0, acc);
            float bias = bq[h * DD + c * 32 + nh * 16 + lr];
            char* qs = lds + LDS_QK + (c & 1) * 16384;
            #pragma unroll
            for (int mt = 0; mt < 2; ++mt)
                #pragma unroll
                for (int r = 0; r < 4; ++r) {
                    int t = mq * 32 + mt * 16 + lg * 4 + r;
                    *(unsigned short*)(qs + t * 64 + swzq(t, (nh * 16 + lr) * 2))
                        = f2bf((acc[mt][r] + bias) * 0.0625f);
                }
        }
        LGKM0(); VMCNT0(); BAR();
        // K_c : phase p=2c+1, consumes chunk 2c+1 (slot 1), issues 2c+2
        issue_chunk(2 * c + 2);
        {
            f32x4 acc[2] = {f32x4{0.f,0.f,0.f,0.f}, f32x4{0.f,0.f,0.f,0.f}};
            proj_mm(1, acc);
            float bias = bk[h * DD + c * 32 + nh * 16 + lr];
            char* ksl = lds + LDS_QK + (c & 1) * 16384 + 8192;
            #pragma unroll
            for (int mt = 0; mt < 2; ++mt)
                #pragma unroll
                for (int r = 0; r < 4; ++r) {
                    int s = mq * 32 + mt * 16 + lg * 4 + r;
                    *(unsigned short*)(ksl + s * 64 + swzq(s, (nh * 16 + lr) * 2))
                        = f2bf(acc[mt][r] + bias);
                }
        }
        LGKM0(); VMCNT0(); BAR();
        // S += Q_c K_c^T (standalone; reads QK slot c&1; safe for 2 more barriers)
        {
            const char* qs  = lds + LDS_QK + (c & 1) * 16384;
            const char* ks2 = qs + 8192;
            short8 qa[2], kb[4];
            #pragma unroll
            for (int mt = 0; mt < 2; ++mt) {
                int row = mq * 32 + mt * 16 + lr;
                qa[mt] = *(const short8*)(qs + row * 64 + swzq(row, lg * 16));
            }
            #pragma unroll
            for (int nt = 0; nt < 4; ++nt) {
                int srow = nh * 64 + nt * 16 + lr;
                kb[nt] = *(const short8*)(ks2 + srow * 64 + swzq(srow, lg * 16));
            }
            #pragma unroll
            for (int mt = 0; mt < 2; ++mt)
                #pragma unroll
                for (int nt = 0; nt < 4; ++nt)
                    sacc[mt][nt] = __builtin_amdgcn_mfma_f32_16x16x32_bf16(qa[mt], kb[nt], sacc[mt][nt], 0, 0, 0);
        }
    }

    // ---- softmax (frees sacc before V phases) ----
    float* redM = (float*)(lds + LDS_RED);
    float* redS = redM + 256;
    {
        float rmax[2][4];
        #pragma unroll
        for (int mt = 0; mt < 2; ++mt)
            #pragma unroll
            for (int r = 0; r < 4; ++r) {
                int t = mq * 32 + mt * 16 + lg * 4 + r;
                float m = -1e30f;
                #pragma unroll
                for (int nt = 0; nt < 4; ++nt) {
                    int s = nh * 64 + nt * 16 + lr;
                    if (s > t) sacc[mt][nt][r] = -1e30f;
                    m = fmaxf(m, sacc[mt][nt][r]);
                }
                m = fmaxf(m, __shfl_xor(m, 1));
                m = fmaxf(m, __shfl_xor(m, 2));
                m = fmaxf(m, __shfl_xor(m, 4));
                m = fmaxf(m, __shfl_xor(m, 8));
                rmax[mt][r] = m;
            }
        if (lr == 0) {
            #pragma unroll
            for (int mt = 0; mt < 2; ++mt)
                #pragma unroll
                for (int r = 0; r < 4; ++r)
                    redM[nh * 128 + mq * 32 + mt * 16 + lg * 4 + r] = rmax[mt][r];
        }
        LGKM0(); BAR();
        float rsum[2][4];
        #pragma unroll
        for (int mt = 0; mt < 2; ++mt)
            #pragma unroll
            for (int r = 0; r < 4; ++r) {
                int t = mq * 32 + mt * 16 + lg * 4 + r;
                float m = fmaxf(redM[t], redM[128 + t]);
                float ssum = 0.f;
                #pragma unroll
                for (int nt = 0; nt < 4; ++nt) {
                    float p = __expf(sacc[mt][nt][r] - m);
                    sacc[mt][nt][r] = p;
                    ssum += p;
                }
                ssum += __shfl_xor(ssum, 1);
                ssum += __shfl_xor(ssum, 2);
                ssum += __shfl_xor(ssum, 4);
                ssum += __shfl_xor(ssum, 8);
                rsum[mt][r] = ssum;
            }
        if (lr == 0) {
            #pragma unroll
            for (int mt = 0; mt < 2; ++mt)
                #pragma unroll
                for (int r = 0; r < 4; ++r)
                    redS[nh * 128 + mq * 32 + mt * 16 + lg * 4 + r] = rsum[mt][r];
        }
        LGKM0(); BAR();
        // P -> [32K,64K): [128 t][256B rows], swizzled (overwrites QK chunks)
        #pragma unroll
        for (int mt = 0; mt < 2; ++mt)
            #pragma unroll
            for (int r = 0; r < 4; ++r) {
                int t = mq * 32 + mt * 16 + lg * 4 + r;
                float inv = 1.0f / (redS[t] + redS[128 + t]);
                #pragma unroll
                for (int nt = 0; nt < 4; ++nt) {
                    int s = nh * 64 + nt * 16 + lr;
                    *(unsigned short*)(lds + LDS_QK + t * 256 + swzr(t, s * 2))
                        = f2bf(sacc[mt][nt][r] * inv);
                }
            }
    }
    LGKM0(); VMCNT0(); BAR();   // P visible; chunk 16 (Wv0) arrived

    // ---- V phases: V kept in registers (bf16-packed C-layout) ----
    uint2 vreg[8][2];
    #pragma unroll
    for (int vc = 0; vc < 8; ++vc) {
        issue_chunk(17 + vc);                 // 17..24 (Wv1..7, Wp0)
        f32x4 acc[2] = {f32x4{0.f,0.f,0.f,0.f}, f32x4{0.f,0.f,0.f,0.f}};
        proj_mm(vc & 1, acc);
        float bias = bv[h * DD + vc * 32 + nh * 16 + lr];
        #pragma unroll
        for (int mt = 0; mt < 2; ++mt) {
            vreg[vc][mt].x = pk2(acc[mt][0] + bias, acc[mt][1] + bias);
            vreg[vc][mt].y = pk2(acc[mt][2] + bias, acc[mt][3] + bias);
        }
        LGKM0(); VMCNT0(); BAR();
    }

    // ---- PV: P-frags read once into regs; per-c VT round trip ----
    short8 pa[2][4];
    #pragma unroll
    for (int mt = 0; mt < 2; ++mt) {
        int row = mq * 32 + mt * 16 + lr;
        #pragma unroll
        for (int ks = 0; ks < 4; ++ks)
            pa[mt][ks] = *(const short8*)(lds + LDS_QK + row * 256 + swzr(row, ks * 64 + lg * 16));
    }
    uint2 obf[8][2];
    #pragma unroll
    for (int c = 0; c < 8; ++c) {
        {   // V^T chunk [32 d][128 s] from vreg
            char* vt = lds + LDS_VT;
            int dl = nh * 16 + lr;
            #pragma unroll
            for (int mt = 0; mt < 2; ++mt) {
                int s0 = mq * 32 + mt * 16 + lg * 4;
                *(uint2*)(vt + dl * 256 + swzr(dl, s0 * 2)) = vreg[c][mt];
            }
        }
        LGKM0(); BAR();
        f32x4 oacc[2] = {f32x4{0.f,0.f,0.f,0.f}, f32x4{0.f,0.f,0.f,0.f}};
        {
            int dl = nh * 16 + lr;
            #pragma unroll
            for (int ks = 0; ks < 4; ++ks) {
                short8 vb = *(const short8*)(lds + LDS_VT + dl * 256 + swzr(dl, ks * 64 + lg * 16));
                oacc[0] = __builtin_amdgcn_mfma_f32_16x16x32_bf16(pa[0][ks], vb, oacc[0], 0, 0, 0);
                oacc[1] = __builtin_amdgcn_mfma_f32_16x16x32_bf16(pa[1][ks], vb, oacc[1], 0, 0, 0);
            }
        }
        #pragma unroll
        for (int mt = 0; mt < 2; ++mt) {
            obf[c][mt].x = pk2(oacc[mt][0], oacc[mt][1]);
            obf[c][mt].y = pk2(oacc[mt][2], oacc[mt][3]);
        }
        LGKM0(); BAR();
    }

    // ---- O -> A-fragments via two 32KB half-stages in the P region ----
    short8 of[2][8];
    #pragma unroll
    for (int dh = 0; dh < 2; ++dh) {
        #pragma unroll
        for (int cc = 0; cc < 4; ++cc) {
            int c = dh * 4 + cc;
            int dl2 = cc * 32 + nh * 16 + lr;   // local d in [0,128)
            #pragma unroll
            for (int mt = 0; mt < 2; ++mt) {
                unsigned vx = obf[c][mt].x, vy = obf[c][mt].y;
                unsigned short vals[4] = {
                    (unsigned short)(vx & 0xffff), (unsigned short)(vx >> 16),
                    (unsigned short)(vy & 0xffff), (unsigned short)(vy >> 16) };
                #pragma unroll
                for (int j = 0; j < 4; ++j) {
                    int t = mq * 32 + mt * 16 + lg * 4 + j;
                    *(unsigned short*)(lds + LDS_QK + t * 256 + swzr(t, dl2 * 2)) = vals[j];
                }
            }
        }
        LGKM0(); BAR();
        #pragma unroll
        for (int mt = 0; mt < 2; ++mt) {
            int row = mq * 32 + mt * 16 + lr;
            #pragma unroll
            for (int ks = 0; ks < 4; ++ks)
                of[mt][dh * 4 + ks] = *(const short8*)(lds + LDS_QK + row * 256 + swzr(row, ks * 64 + lg * 16));
        }
        LGKM0(); BAR();
    }
    VMCNT0();   // chunk 24 (Wp0, issued in V phase 7) arrived

    // ---- OUT = O * Wp^T + bp -> global fp32 ----
    #pragma unroll
    for (int m = 0; m < 8; ++m) {
        if (m < 7) issue_chunk(25 + m);       // 25..31
        f32x4 acc[2] = {f32x4{0.f,0.f,0.f,0.f}, f32x4{0.f,0.f,0.f,0.f}};
        {
            const char* Wb = lds + LDS_W + (m & 1) * 16384;
            const int br = nh * 16 + lr;
            #pragma unroll
            for (int ks = 0; ks < 8; ++ks) {
                short8 b0 = *(const short8*)(Wb + br * 512 + swzr(br, ks * 64 + lg * 16));
                acc[0] = __builtin_amdgcn_mfma_f32_16x16x32_bf16(of[0][ks], b0, acc[0], 0, 0, 0);
                acc[1] = __builtin_amdgcn_mfma_f32_16x16x32_bf16(of[1][ks], b0, acc[1], 0, 0, 0);
            }
        }
        int e = m * 32 + nh * 16 + lr;
        float bias = bp[e];
        #pragma unroll
        for (int mt = 0; mt < 2; ++mt)
            #pragma unroll
            for (int r = 0; r < 4; ++r) {
                int t = mq * 32 + mt * 16 + lg * 4 + r;
                out[((size_t)bid * TT + t) * DD + e] = acc[mt][r] + bias;
            }
        if (m < 7) { LGKM0(); VMCNT8(); BAR(); }
    }
}

extern "C" void kernel_launch(void* const* d_in, const int* in_sizes, int n_in,
                              void* d_out, int out_size, void* d_ws, size_t ws_size,
                              hipStream_t stream) {
    (void)in_sizes; (void)n_in; (void)out_size; (void)ws_size; // needs ws_size >= 20054016
    const float* x  = (const float*)d_in[0];
    const float* Wq = (const float*)d_in[1];
    const float* bq = (const float*)d_in[2];
    const float* Wk = (const float*)d_in[3];
    const float* bk = (const float*)d_in[4];
    const float* Wv = (const float*)d_in[5];
    const float* bv = (const float*)d_in[6];
    const float* Wp = (const float*)d_in[7];
    const float* bp = (const float*)d_in[8];
    char* ws = (char*)d_ws;

    convert_pre<<<dim3(2048), dim3(256), 0, stream>>>(x, Wq, Wk, Wv, Wp, ws);
    hipFuncSetAttribute((const void*)mha_fused,
                        hipFuncAttributeMaxDynamicSharedMemorySize, LDS_SIZE);
    mha_fused<<<dim3(2048), dim3(512), LDS_SIZE, stream>>>(
        ws, bq, bk, bv, bp, (float*)d_out);
}

// Round 4
// 293.502 us; speedup vs baseline: 2.0044x; 2.0044x over previous
//
#include <hip/hip_runtime.h>
#include <hip/hip_bf16.h>
#include <stdint.h>

// Fused causal MHA, B=256,T=128,H=8,D=256,C=256. One block per (h,b).
// Round 4: round-3 structure (X in registers as A-fragments), spill fixed:
// __launch_bounds__(512,2) -> 128 VGPR cap; obf/O-restage replaced by a
// per-chunk 8KB LDS transpose strip; LDS = 80KB exactly -> 2 blocks/CU.

#define TT 128
#define CC 256
#define DD 256

typedef __attribute__((ext_vector_type(8))) short short8;
typedef __attribute__((ext_vector_type(4))) float f32x4;

// LDS map (81920 B):
//   [0,32K)    W ring: 2 x 16KB (32 rows x 512B, swizzled by row&7)
//   [32K,64K)  QK chunk ring 2x16KB (Q[128][64B]+K[128][64B]) -> P[128][256B]
//   [64K,72K)  VT chunk [32 d][256B]  (softmax scratch overlaid here)
//   [72K,80K)  O transpose strip [128 t][64B]
#define LDS_W    0
#define LDS_QK   32768
#define LDS_VT   65536
#define LDS_OS   73728
#define LDS_RED  65536
#define LDS_SIZE 81920

// ws map (needs >= 20054016 B)
#define WS_X    0u
#define WS_WQ   16777216u
#define WS_WK   (16777216u + 1048576u)
#define WS_WV   (16777216u + 2097152u)
#define WS_WP   (16777216u + 3145728u)

#define VMCNT0() asm volatile("s_waitcnt vmcnt(0)" ::: "memory")
#define VMCNT8() asm volatile("s_waitcnt vmcnt(8)" ::: "memory")
#define LGKM0()  asm volatile("s_waitcnt lgkmcnt(0)" ::: "memory")
#define BAR()    do { asm volatile("" ::: "memory"); __builtin_amdgcn_s_barrier(); asm volatile("" ::: "memory"); } while (0)

__device__ __forceinline__ unsigned short f2bf(float x) {
    union { float f; unsigned u; } v; v.f = x;
    unsigned r = v.u + 0x7FFFu + ((v.u >> 16) & 1u);
    return (unsigned short)(r >> 16);
}
__device__ __forceinline__ unsigned pk2(float a, float b) {
    return (unsigned)f2bf(a) | ((unsigned)f2bf(b) << 16);
}
__device__ __forceinline__ int swzr(int row, int byteInRow) {   // 512B/256B rows
    return byteInRow ^ ((row & 7) << 4);
}
__device__ __forceinline__ int swzq(int row, int byteInRow) {   // 64B rows
    return byteInRow ^ (((row >> 2) & 3) << 4);
}

typedef __attribute__((address_space(3))) uint32_t lds_u32;
typedef __attribute__((address_space(1))) const uint32_t glb_u32;

// ---------------- pre-convert: fp32 -> bf16, pre-swizzled 512B rows ----------------
__global__ void convert_pre(const float* __restrict__ x,
                            const float* __restrict__ Wq, const float* __restrict__ Wk,
                            const float* __restrict__ Wv, const float* __restrict__ Wp,
                            char* __restrict__ ws) {
    const int NX = 2097152, NW = 131072, NP = 16384;   // float4 counts
    const int total = NX + 3 * NW + NP;
    for (int i = blockIdx.x * blockDim.x + threadIdx.x; i < total;
         i += gridDim.x * blockDim.x) {
        const float4* src; size_t ob; int li;
        if (i < NX)              { src = (const float4*)x;  ob = WS_X;  li = i; }
        else if (i < NX + NW)    { src = (const float4*)Wq; ob = WS_WQ; li = i - NX; }
        else if (i < NX + 2*NW)  { src = (const float4*)Wk; ob = WS_WK; li = i - NX - NW; }
        else if (i < NX + 3*NW)  { src = (const float4*)Wv; ob = WS_WV; li = i - NX - 2*NW; }
        else                     { src = (const float4*)Wp; ob = WS_WP; li = i - NX - 3*NW; }
        float4 v = src[li];
        uint2 u; u.x = pk2(v.x, v.y); u.y = pk2(v.z, v.w);
        int row = li >> 6, c4 = li & 63;
        *(uint2*)(ws + ob + (size_t)row * 512 + ((c4 * 8) ^ ((row & 7) << 4))) = u;
    }
}

// ---------------- main fused kernel ----------------
__global__ __launch_bounds__(512, 2) void mha_fused(
    const char* __restrict__ ws,
    const float* __restrict__ bq, const float* __restrict__ bk,
    const float* __restrict__ bv, const float* __restrict__ bp,
    float* __restrict__ out)
{
    extern __shared__ __align__(16) char lds[];
    const int tid = threadIdx.x;
    const int w  = tid >> 6, l = tid & 63;
    const int lg = l >> 4, lr = l & 15;
    const int mq = w & 3, nh = w >> 2;        // 4 M-waves x 2 N-waves
    const int bid = blockIdx.x;
    const int h = bid >> 8, b = bid & 255;

    auto gl16 = [&](const char* g, int loff) {
        __builtin_amdgcn_global_load_lds((glb_u32*)g, (lds_u32*)(lds + loff), 16, 0, 0);
    };
    // chunk stream: 0..15 = Wq[c]/Wk[c] interleaved, 16..23 = Wv, 24..31 = Wp
    auto chunk_src = [&](int idx) -> const char* {
        if (idx < 16) {
            int c = idx >> 1;
            return ws + ((idx & 1) ? WS_WK : WS_WQ) + (size_t)h * 131072 + (size_t)c * 16384;
        } else if (idx < 24) {
            return ws + WS_WV + (size_t)h * 131072 + (size_t)(idx - 16) * 16384;
        }
        return ws + WS_WP + (size_t)(idx - 24) * 16384;
    };
    auto issue_chunk = [&](int idx) {
        const char* g = chunk_src(idx) + tid * 16;
        int loff = LDS_W + (idx & 1) * 16384 + tid * 16;
        gl16(g, loff);
        gl16(g + 8192, loff + 8192);
    };

    // ---- X as A-fragments in registers (32 VGPR), direct per-lane loads ----
    short8 xf[2][8];
    {
        const char* xp = ws + WS_X + (size_t)b * 65536;
        #pragma unroll
        for (int mt = 0; mt < 2; ++mt) {
            int t = mq * 32 + mt * 16 + lr;
            #pragma unroll
            for (int ks = 0; ks < 8; ++ks)
                xf[mt][ks] = *(const short8*)(xp + t * 512 + swzr(t, ks * 64 + lg * 16));
        }
    }
    issue_chunk(0);
    VMCNT0(); BAR();

    // proj: acc[mt] += X[32t x 256] * Wchunk[32 rows]^T (wave tile 32t x 16n)
    auto proj_mm = [&](int slot, f32x4* acc) {
        const char* Wb = lds + LDS_W + slot * 16384;
        const int br = nh * 16 + lr;
        #pragma unroll
        for (int ks = 0; ks < 8; ++ks) {
            short8 b0 = *(const short8*)(Wb + br * 512 + swzr(br, ks * 64 + lg * 16));
            acc[0] = __builtin_amdgcn_mfma_f32_16x16x32_bf16(xf[0][ks], b0, acc[0], 0, 0, 0);
            acc[1] = __builtin_amdgcn_mfma_f32_16x16x32_bf16(xf[1][ks], b0, acc[1], 0, 0, 0);
        }
    };

    f32x4 sacc[2][4];
    #pragma unroll
    for (int i = 0; i < 2; ++i)
        #pragma unroll
        for (int j = 0; j < 4; ++j) sacc[i][j] = f32x4{0.f,0.f,0.f,0.f};

    // ---- QK phases ----
    #pragma unroll
    for (int c = 0; c < 8; ++c) {
        // Q_c : consumes chunk 2c (slot 0), issues 2c+1
        issue_chunk(2 * c + 1);
        {
            f32x4 acc[2] = {f32x4{0.f,0.f,0.f,0.f}, f32x4{0.f,0.f,0.f,0.f}};
            proj_mm(0, acc);
            float bias = bq[h * DD + c * 32 + nh * 16 + lr];
            char* qs = lds + LDS_QK + (c & 1) * 16384;
            #pragma unroll
            for (int mt = 0; mt < 2; ++mt)
                #pragma unroll
                for (int r = 0; r < 4; ++r) {
                    int t = mq * 32 + mt * 16 + lg * 4 + r;
                    *(unsigned short*)(qs + t * 64 + swzq(t, (nh * 16 + lr) * 2))
                        = f2bf((acc[mt][r] + bias) * 0.0625f);
                }
        }
        LGKM0(); VMCNT0(); BAR();
        // K_c : consumes chunk 2c+1 (slot 1), issues 2c+2
        issue_chunk(2 * c + 2);
        {
            f32x4 acc[2] = {f32x4{0.f,0.f,0.f,0.f}, f32x4{0.f,0.f,0.f,0.f}};
            proj_mm(1, acc);
            float bias = bk[h * DD + c * 32 + nh * 16 + lr];
            char* ksl = lds + LDS_QK + (c & 1) * 16384 + 8192;
            #pragma unroll
            for (int mt = 0; mt < 2; ++mt)
                #pragma unroll
                for (int r = 0; r < 4; ++r) {
                    int s = mq * 32 + mt * 16 + lg * 4 + r;
                    *(unsigned short*)(ksl + s * 64 + swzq(s, (nh * 16 + lr) * 2))
                        = f2bf(acc[mt][r] + bias);
                }
        }
        LGKM0(); VMCNT0(); BAR();
        // S += Q_c K_c^T (reads QK slot c&1; disjoint from next phases' writes)
        {
            const char* qs  = lds + LDS_QK + (c & 1) * 16384;
            const char* ks2 = qs + 8192;
            short8 qa[2], kb[4];
            #pragma unroll
            for (int mt = 0; mt < 2; ++mt) {
                int row = mq * 32 + mt * 16 + lr;
                qa[mt] = *(const short8*)(qs + row * 64 + swzq(row, lg * 16));
            }
            #pragma unroll
            for (int nt = 0; nt < 4; ++nt) {
                int srow = nh * 64 + nt * 16 + lr;
                kb[nt] = *(const short8*)(ks2 + srow * 64 + swzq(srow, lg * 16));
            }
            #pragma unroll
            for (int mt = 0; mt < 2; ++mt)
                #pragma unroll
                for (int nt = 0; nt < 4; ++nt)
                    sacc[mt][nt] = __builtin_amdgcn_mfma_f32_16x16x32_bf16(qa[mt], kb[nt], sacc[mt][nt], 0, 0, 0);
        }
    }

    // ---- softmax (scratch overlaid on VT region; frees sacc before V phases) ----
    float* redM = (float*)(lds + LDS_RED);
    float* redS = redM + 256;
    {
        float rmax[2][4];
        #pragma unroll
        for (int mt = 0; mt < 2; ++mt)
            #pragma unroll
            for (int r = 0; r < 4; ++r) {
                int t = mq * 32 + mt * 16 + lg * 4 + r;
                float m = -1e30f;
                #pragma unroll
                for (int nt = 0; nt < 4; ++nt) {
                    int s = nh * 64 + nt * 16 + lr;
                    if (s > t) sacc[mt][nt][r] = -1e30f;
                    m = fmaxf(m, sacc[mt][nt][r]);
                }
                m = fmaxf(m, __shfl_xor(m, 1));
                m = fmaxf(m, __shfl_xor(m, 2));
                m = fmaxf(m, __shfl_xor(m, 4));
                m = fmaxf(m, __shfl_xor(m, 8));
                rmax[mt][r] = m;
            }
        if (lr == 0) {
            #pragma unroll
            for (int mt = 0; mt < 2; ++mt)
                #pragma unroll
                for (int r = 0; r < 4; ++r)
                    redM[nh * 128 + mq * 32 + mt * 16 + lg * 4 + r] = rmax[mt][r];
        }
        LGKM0(); BAR();
        float rsum[2][4];
        #pragma unroll
        for (int mt = 0; mt < 2; ++mt)
            #pragma unroll
            for (int r = 0; r < 4; ++r) {
                int t = mq * 32 + mt * 16 + lg * 4 + r;
                float m = fmaxf(redM[t], redM[128 + t]);
                float ssum = 0.f;
                #pragma unroll
                for (int nt = 0; nt < 4; ++nt) {
                    float p = __expf(sacc[mt][nt][r] - m);
                    sacc[mt][nt][r] = p;
                    ssum += p;
                }
                ssum += __shfl_xor(ssum, 1);
                ssum += __shfl_xor(ssum, 2);
                ssum += __shfl_xor(ssum, 4);
                ssum += __shfl_xor(ssum, 8);
                rsum[mt][r] = ssum;
            }
        if (lr == 0) {
            #pragma unroll
            for (int mt = 0; mt < 2; ++mt)
                #pragma unroll
                for (int r = 0; r < 4; ++r)
                    redS[nh * 128 + mq * 32 + mt * 16 + lg * 4 + r] = rsum[mt][r];
        }
        LGKM0(); BAR();
        // P -> [32K,64K): [128 t][256B rows], swizzled (overwrites QK ring)
        #pragma unroll
        for (int mt = 0; mt < 2; ++mt)
            #pragma unroll
            for (int r = 0; r < 4; ++r) {
                int t = mq * 32 + mt * 16 + lg * 4 + r;
                float inv = 1.0f / (redS[t] + redS[128 + t]);
                #pragma unroll
                for (int nt = 0; nt < 4; ++nt) {
                    int s = nh * 64 + nt * 16 + lr;
                    *(unsigned short*)(lds + LDS_QK + t * 256 + swzr(t, s * 2))
                        = f2bf(sacc[mt][nt][r] * inv);
                }
            }
    }
    LGKM0(); VMCNT0(); BAR();   // P visible; chunk 16 (Wv0) arrived

    // ---- V phases: V kept in registers (bf16-packed C-layout) ----
    uint2 vreg[8][2];
    #pragma unroll
    for (int vc = 0; vc < 8; ++vc) {
        issue_chunk(17 + vc);                 // 17..24 (Wv1..7, Wp0)
        f32x4 acc[2] = {f32x4{0.f,0.f,0.f,0.f}, f32x4{0.f,0.f,0.f,0.f}};
        proj_mm(vc & 1, acc);
        float bias = bv[h * DD + vc * 32 + nh * 16 + lr];
        #pragma unroll
        for (int mt = 0; mt < 2; ++mt) {
            vreg[vc][mt].x = pk2(acc[mt][0] + bias, acc[mt][1] + bias);
            vreg[vc][mt].y = pk2(acc[mt][2] + bias, acc[mt][3] + bias);
        }
        LGKM0(); VMCNT0(); BAR();
    }

    // ---- PV with per-chunk O transpose through the 8KB strip ----
    short8 pa[2][4];
    #pragma unroll
    for (int mt = 0; mt < 2; ++mt) {
        int row = mq * 32 + mt * 16 + lr;
        #pragma unroll
        for (int ks = 0; ks < 4; ++ks)
            pa[mt][ks] = *(const short8*)(lds + LDS_QK + row * 256 + swzr(row, ks * 64 + lg * 16));
    }
    short8 of[2][8];
    const int dl = nh * 16 + lr;
    #pragma unroll
    for (int c = 0; c < 8; ++c) {
        // window A: write VT_c; read back of_{c-1} from the O strip
        #pragma unroll
        for (int mt = 0; mt < 2; ++mt) {
            int s0 = mq * 32 + mt * 16 + lg * 4;
            *(uint2*)(lds + LDS_VT + dl * 256 + swzr(dl, s0 * 2)) = vreg[c][mt];
        }
        if (c > 0) {
            #pragma unroll
            for (int mt = 0; mt < 2; ++mt) {
                int row = mq * 32 + mt * 16 + lr;
                of[mt][c - 1] = *(const short8*)(lds + LDS_OS + row * 64 + swzq(row, lg * 16));
            }
        }
        LGKM0(); BAR();
        // window B: PV MFMAs (P x VT_c) ; write O d-band c to the strip
        f32x4 oacc[2] = {f32x4{0.f,0.f,0.f,0.f}, f32x4{0.f,0.f,0.f,0.f}};
        #pragma unroll
        for (int ks = 0; ks < 4; ++ks) {
            short8 vb = *(const short8*)(lds + LDS_VT + dl * 256 + swzr(dl, ks * 64 + lg * 16));
            oacc[0] = __builtin_amdgcn_mfma_f32_16x16x32_bf16(pa[0][ks], vb, oacc[0], 0, 0, 0);
            oacc[1] = __builtin_amdgcn_mfma_f32_16x16x32_bf16(pa[1][ks], vb, oacc[1], 0, 0, 0);
        }
        #pragma unroll
        for (int mt = 0; mt < 2; ++mt)
            #pragma unroll
            for (int r = 0; r < 4; ++r) {
                int t = mq * 32 + mt * 16 + lg * 4 + r;
                *(unsigned short*)(lds + LDS_OS + t * 64 + swzq(t, (nh * 16 + lr) * 2))
                    = f2bf(oacc[mt][r]);
            }
        LGKM0(); BAR();
    }
    // tail: read of_{7}
    #pragma unroll
    for (int mt = 0; mt < 2; ++mt) {
        int row = mq * 32 + mt * 16 + lr;
        of[mt][7] = *(const short8*)(lds + LDS_OS + row * 64 + swzq(row, lg * 16));
    }
    VMCNT0();   // chunk 24 (Wp0, issued in V phase 7) arrived

    // ---- OUT = O * Wp^T + bp -> global fp32 ----
    #pragma unroll
    for (int m = 0; m < 8; ++m) {
        if (m < 7) issue_chunk(25 + m);       // 25..31
        f32x4 acc[2] = {f32x4{0.f,0.f,0.f,0.f}, f32x4{0.f,0.f,0.f,0.f}};
        {
            const char* Wb = lds + LDS_W + (m & 1) * 16384;
            const int br = nh * 16 + lr;
            #pragma unroll
            for (int ks = 0; ks < 8; ++ks) {
                short8 b0 = *(const short8*)(Wb + br * 512 + swzr(br, ks * 64 + lg * 16));
                acc[0] = __builtin_amdgcn_mfma_f32_16x16x32_bf16(of[0][ks], b0, acc[0], 0, 0, 0);
                acc[1] = __builtin_amdgcn_mfma_f32_16x16x32_bf16(of[1][ks], b0, acc[1], 0, 0, 0);
            }
        }
        int e = m * 32 + nh * 16 + lr;
        float bias = bp[e];
        #pragma unroll
        for (int mt = 0; mt < 2; ++mt)
            #pragma unroll
            for (int r = 0; r < 4; ++r) {
                int t = mq * 32 + mt * 16 + lg * 4 + r;
                out[((size_t)bid * TT + t) * DD + e] = acc[mt][r] + bias;
            }
        if (m < 7) { LGKM0(); VMCNT8(); BAR(); }
    }
}

extern "C" void kernel_launch(void* const* d_in, const int* in_sizes, int n_in,
                              void* d_out, int out_size, void* d_ws, size_t ws_size,
                              hipStream_t stream) {
    (void)in_sizes; (void)n_in; (void)out_size; (void)ws_size; // needs ws_size >= 20054016
    const float* x  = (const float*)d_in[0];
    const float* Wq = (const float*)d_in[1];
    const float* bq = (const float*)d_in[2];
    const float* Wk = (const float*)d_in[3];
    const float* bk = (const float*)d_in[4];
    const float* Wv = (const float*)d_in[5];
    const float* bv = (const float*)d_in[6];
    const float* Wp = (const float*)d_in[7];
    const float* bp = (const float*)d_in[8];
    char* ws = (char*)d_ws;

    convert_pre<<<dim3(2048), dim3(256), 0, stream>>>(x, Wq, Wk, Wv, Wp, ws);
    hipFuncSetAttribute((const void*)mha_fused,
                        hipFuncAttributeMaxDynamicSharedMemorySize, LDS_SIZE);
    mha_fused<<<dim3(2048), dim3(512), LDS_SIZE, stream>>>(
        ws, bq, bk, bv, bp, (float*)d_out);
}